// Round 14
// baseline (124.125 us; speedup 1.0000x reference)
//
#include <hip/hip_runtime.h>

// ImageLRU as one GEMM: y[r,:] = W @ x[r,:], W (1024x1024, block-lower-tri)
// built on device. R14 = R7 skeleton with BK=64 K-steps:
//   Diagnosis R13: gemm is latency/overhead-bound at 16 MFMA/barrier; R4's
//   proven 966-TF config had 32 MFMA/barrier. Restore that density at 1-term
//   work: each step stages a 128x64 A tile (two kg-major 4096-ushort tiles,
//   4 gld_lds16/thread, dbuf 32 KB LDS) and computes 32 MFMA/wave between one
//   barrier-pair. W-fragments register-direct from L2-resident tiled Wh
//   (R8-proven), double-buffered in NAMED register sets, loop unrolled x2.
//   1-term precision: y = bf16(X)*bf16(W)  (absmax 8192, thr 32768).

namespace {

typedef __attribute__((ext_vector_type(8))) short short8v;
typedef __attribute__((ext_vector_type(4))) float f32x4;

__device__ inline unsigned short f2bf_rne(float f) {
    unsigned u = __builtin_bit_cast(unsigned, f);
    u += 0x7fffu + ((u >> 16) & 1u);
    return (unsigned short)(u >> 16);
}

__device__ inline void gld_lds16(const unsigned short* g, unsigned short* l) {
    __builtin_amdgcn_global_load_lds(
        (const __attribute__((address_space(1))) unsigned int*)g,
        (__attribute__((address_space(3))) unsigned int*)l, 16, 0, 0);
}

// kg-major tile layout ([128 rows][32 k] bf16, 4096 ushorts): elem (row,k) at
//   base + ((k>>3)<<10) + (row<<3) + (k&7)
// Proven conflict-free for gld_lds staging and ds_read_b128 fragments (R3-R7).
// A 64-K step = two consecutive tiles, contiguous 8192 ushorts.

// ------------- prep: blocks [0,4096) build W; [4096,12288) split X ----------
__global__ __launch_bounds__(256) void prep_kernel(
    const float* __restrict__ X,
    const float* __restrict__ Lre, const float* __restrict__ Lim,
    const float* __restrict__ Bre, const float* __restrict__ Bim,
    const float* __restrict__ Cre, const float* __restrict__ Cim,
    const float* __restrict__ Dm,
    unsigned short* __restrict__ Wh, unsigned short* __restrict__ Xh)
{
    const int t = threadIdx.x;

    if (blockIdx.x < 4096) {
        // ---- build W block (i,j): T = prod of stage factors; W = Re(C*T)+D ----
        const int i = blockIdx.x >> 6, j = blockIdx.x & 63;
        const int k = t >> 4, l = t & 15;

        const int n_g = i * 16 + k;        // W row (n dim)
        const int k_g = j * 16 + l;        // W col (k dim)
        const size_t widx = (((size_t)((n_g >> 7) * 32 + (k_g >> 5))) << 12)
                          + (((k_g >> 3) & 3) << 10) + ((n_g & 127) << 3) + (k_g & 7);

        if (j > i) { Wh[widx] = 0; return; }

        __shared__ float2 Bs[16][16];
        __shared__ float2 M[16][16];
        Bs[k][l] = make_float2(Bre[t], Bim[t]);
        M[k][l]  = make_float2(k == l ? 1.f : 0.f, 0.f);
        const int delta = i - j;
        __syncthreads();

        #pragma unroll
        for (int d = 0; d < 6; ++d) {
            const int s = 1 << d;
            if (delta & s) {
                const float lr = Lre[k], li = Lim[k];
                const float2 m0 = M[k][l];
                M[k][l] = make_float2(lr * m0.x - li * m0.y, lr * m0.y + li * m0.x);
                __syncthreads();
            } else if (j + (delta & (s - 1)) >= s) {
                float2 acc = make_float2(0.f, 0.f);
                #pragma unroll
                for (int m = 0; m < 16; ++m) {
                    const float2 b = Bs[k][m], v = M[m][l];
                    acc.x += b.x * v.x - b.y * v.y;
                    acc.y += b.x * v.y + b.y * v.x;
                }
                __syncthreads();
                M[k][l] = acc;
                __syncthreads();
            }
        }

        float w = 0.f;
        #pragma unroll
        for (int m = 0; m < 16; ++m) {
            const float2 v = M[m][l];
            w += Cre[k * 16 + m] * v.x - Cim[k * 16 + m] * v.y;
        }
        if (i == j) w += Dm[t];
        Wh[widx] = f2bf_rne(w);
    } else {
        // ---- split X tile (mt, kc) -> bf16 kg-major tiled layout ----
        const int sid = blockIdx.x - 4096;
        const int mt = sid >> 5;           // 128-row tile (0..255)
        const int kc = sid & 31;           // 32-col chunk
        const size_t tb = ((size_t)(mt * 32 + kc)) << 12;

        #pragma unroll
        for (int p = 0; p < 4; ++p) {
            const int f = p * 256 + t;          // float4 id in [0,1024)
            const int row = f >> 3, c4 = f & 7;
            const float4 v = *reinterpret_cast<const float4*>(
                X + (size_t)(mt * 128 + row) * 1024 + kc * 32 + c4 * 4);
            ushort4 hv;
            hv.x = f2bf_rne(v.x);
            hv.y = f2bf_rne(v.y);
            hv.z = f2bf_rne(v.z);
            hv.w = f2bf_rne(v.w);
            const size_t o = tb + ((size_t)(c4 >> 1) << 10) + (row << 3) + ((c4 & 1) << 2);
            *reinterpret_cast<ushort4*>(Xh + o) = hv;
        }
    }
}

// ---- main GEMM: BK=64, A dbuf LDS (32 KB), W reg-direct, 32 MFMA/barrier ---
__global__ __launch_bounds__(256) void gemm_bk64_kernel(
    const unsigned short* __restrict__ Xh,
    const unsigned short* __restrict__ Wh,
    float* __restrict__ Y, int mtiles)
{
    __shared__ alignas(16) unsigned short sA[2][8192];   // 32 KB

    const int bid = blockIdx.x;
    const int nb = 7 - bid / mtiles;   // heavy N-tiles first (LPT)
    const int mt = bid % mtiles;
    const int t = threadIdx.x;
    const int wid = t >> 6, lane = t & 63;
    const int wr = wid >> 1, wc = wid & 1;
    const int l15 = lane & 15, lg = lane >> 4;
    const int nsteps = (nb + 1) * 2;   // 64-K steps (always even, >= 2)

    f32x4 acc[4][4] = {};

    // A-frag offsets within one 4096-ushort tile (ks adds 4096)
    int afo[4];
    #pragma unroll
    for (int mm = 0; mm < 4; ++mm)
        afo[mm] = (lg << 10) + ((wr * 64 + mm * 16 + l15) << 3);
    // W-frag offsets within one 4096-ushort tile
    int wfo[4];
    #pragma unroll
    for (int nn = 0; nn < 4; ++nn)
        wfo[nn] = (lg << 10) + ((wc * 64 + nn * 16 + l15) << 3);

    auto stageA = [&](unsigned short* buf, int s) {   // 16 KB via 4 gld_lds16
        const size_t xb = ((size_t)(mt * 32 + s * 2)) << 12;
        #pragma unroll
        for (int p = 0; p < 4; ++p) {
            const int e8 = (p * 256 + t) * 8;
            gld_lds16(Xh + xb + e8, buf + e8);
        }
    };

    // named W register sets: w0a/w0b = step-even ks0/ks1, w1a/w1b = step-odd
    short8v w0a[4], w0b[4], w1a[4], w1b[4];
    auto loadW0 = [&](int s) {
        const size_t wb = ((size_t)(nb * 32 + s * 2)) << 12;
        #pragma unroll
        for (int nn = 0; nn < 4; ++nn) {
            w0a[nn] = *reinterpret_cast<const short8v*>(Wh + wb + wfo[nn]);
            w0b[nn] = *reinterpret_cast<const short8v*>(Wh + wb + 4096 + wfo[nn]);
        }
    };
    auto loadW1 = [&](int s) {
        const size_t wb = ((size_t)(nb * 32 + s * 2)) << 12;
        #pragma unroll
        for (int nn = 0; nn < 4; ++nn) {
            w1a[nn] = *reinterpret_cast<const short8v*>(Wh + wb + wfo[nn]);
            w1b[nn] = *reinterpret_cast<const short8v*>(Wh + wb + 4096 + wfo[nn]);
        }
    };

    auto compute = [&](const unsigned short* buf, const short8v* wa,
                       const short8v* wb2) {
        short8v ah[4];
        #pragma unroll
        for (int mm = 0; mm < 4; ++mm)
            ah[mm] = *reinterpret_cast<const short8v*>(buf + afo[mm]);
        #pragma unroll
        for (int mm = 0; mm < 4; ++mm)
            #pragma unroll
            for (int nn = 0; nn < 4; ++nn)
                acc[mm][nn] = __builtin_amdgcn_mfma_f32_16x16x32_bf16(
                    ah[mm], wa[nn], acc[mm][nn], 0, 0, 0);
        #pragma unroll
        for (int mm = 0; mm < 4; ++mm)
            ah[mm] = *reinterpret_cast<const short8v*>(buf + 4096 + afo[mm]);
        #pragma unroll
        for (int mm = 0; mm < 4; ++mm)
            #pragma unroll
            for (int nn = 0; nn < 4; ++nn)
                acc[mm][nn] = __builtin_amdgcn_mfma_f32_16x16x32_bf16(
                    ah[mm], wb2[nn], acc[mm][nn], 0, 0, 0);
    };

    // prologue: step 0 in flight
    stageA(sA[0], 0);
    loadW0(0);
    __syncthreads();                   // vmcnt(0): sA[0] + w0 ready

    for (int s = 0; s < nsteps; s += 2) {
        // even step: prefetch s+1 (always exists: nsteps even), compute s
        stageA(sA[1], s + 1);
        loadW1(s + 1);
        compute(sA[0], w0a, w0b);
        __syncthreads();               // sA[0] reads done; sA[1]+w1 landed

        // odd step: prefetch s+2 if any, compute s+1
        if (s + 2 < nsteps) {
            stageA(sA[0], s + 2);
            loadW0(s + 2);
        }
        compute(sA[1], w1a, w1b);
        __syncthreads();               // sA[1] reads done; sA[0]+w0 landed
    }

    // ---- epilogue: C/D layout col=lane&15, row=(lane>>4)*4+q ----
    #pragma unroll
    for (int mm = 0; mm < 4; ++mm) {
        const int grow = mt * 128 + wr * 64 + mm * 16 + lg * 4;
        #pragma unroll
        for (int nn = 0; nn < 4; ++nn) {
            const int gcol = nb * 128 + wc * 64 + nn * 16 + l15;
            #pragma unroll
            for (int q = 0; q < 4; ++q)
                Y[(size_t)(grow + q) * 1024 + gcol] = acc[mm][nn][q];
        }
    }
}

} // namespace

extern "C" void kernel_launch(void* const* d_in, const int* in_sizes, int n_in,
                              void* d_out, int out_size, void* d_ws, size_t ws_size,
                              hipStream_t stream) {
    const float* x   = (const float*)d_in[0];
    const float* Lre = (const float*)d_in[1];
    const float* Lim = (const float*)d_in[2];
    const float* Bre = (const float*)d_in[3];
    const float* Bim = (const float*)d_in[4];
    const float* Cre = (const float*)d_in[5];
    const float* Cim = (const float*)d_in[6];
    const float* Dm  = (const float*)d_in[7];
    float* y = (float*)d_out;

    const int positions = in_sizes[0] / 1024;          // 32768
    const int mtiles = positions / 128;                // 256

    unsigned short* Wh = (unsigned short*)d_ws;        // 2 MB
    unsigned short* Xh = Wh + 1024 * 1024;             // 64 MB

    prep_kernel<<<4096 + mtiles * 32, 256, 0, stream>>>(
        x, Lre, Lim, Bre, Bim, Cre, Cim, Dm, Wh, Xh);
    gemm_bk64_kernel<<<mtiles * 8, 256, 0, stream>>>(Xh, Wh, y, mtiles);
}

// Round 15
// 119.608 us; speedup vs baseline: 1.0378x; 1.0378x over previous
//
#include <hip/hip_runtime.h>

// ImageLRU as one GEMM: y[r,:] = W @ x[r,:], W (1024x1024, block-lower-tri)
// built on device. R15: counted-vmcnt triple-buffered GEMM (T3/T4 minimum):
//   BM=128 x BN=256, BK=32, 256 thr (4 waves, 2Mx2N, 64x128/wave, acc[4][8]).
//   LDS: 3 bufs x (A 8KB + B 16KB) = 72 KB -> 2 blocks/CU.
//   Pipeline: during tile t stage tile t+2 (6 gld_lds/thread); at boundary
//   s_waitcnt vmcnt(6) -- t+1 landed, t+2's 6 loads STAY IN FLIGHT across the
//   barrier (the m218 lever all prior rounds missed; vmcnt(0) only into the
//   last tile). One barrier per K-tile; ds_reads are C++ (compiler lgkm).
//   W in [256n][32k] tiles (L2-resident); Xh layout unchanged from R7.
//   1-term precision: y = bf16(X)*bf16(W)  (absmax 8192, thr 32768).

namespace {

typedef __attribute__((ext_vector_type(8))) short short8v;
typedef __attribute__((ext_vector_type(4))) float f32x4;

__device__ inline unsigned short f2bf_rne(float f) {
    unsigned u = __builtin_bit_cast(unsigned, f);
    u += 0x7fffu + ((u >> 16) & 1u);
    return (unsigned short)(u >> 16);
}

__device__ inline void gld_lds16(const unsigned short* g, unsigned short* l) {
    __builtin_amdgcn_global_load_lds(
        (const __attribute__((address_space(1))) unsigned int*)g,
        (__attribute__((address_space(3))) unsigned int*)l, 16, 0, 0);
}

// Xh tile ([128 rows][32 k], 4096 ushorts, kg-major): (row,k) at
//   base + ((k>>3)<<10) + (row<<3) + (k&7)            [unchanged from R7]
// W  tile ([256 n][32 k], 8192 ushorts, kg-major): (n,k) at
//   base + ((k>>3)<<11) + (n<<3) + (k&7)

// ------------- prep: blocks [0,4096) build W; [4096,12288) split X ----------
__global__ __launch_bounds__(256) void prep_kernel(
    const float* __restrict__ X,
    const float* __restrict__ Lre, const float* __restrict__ Lim,
    const float* __restrict__ Bre, const float* __restrict__ Bim,
    const float* __restrict__ Cre, const float* __restrict__ Cim,
    const float* __restrict__ Dm,
    unsigned short* __restrict__ Wh, unsigned short* __restrict__ Xh)
{
    const int t = threadIdx.x;

    if (blockIdx.x < 4096) {
        // ---- build W block (i,j): T = prod of stage factors; W = Re(C*T)+D ----
        const int i = blockIdx.x >> 6, j = blockIdx.x & 63;
        const int k = t >> 4, l = t & 15;

        const int n_g = i * 16 + k;        // W row (n dim)
        const int k_g = j * 16 + l;        // W col (k dim)
        const size_t widx = (((size_t)((n_g >> 8) * 32 + (k_g >> 5))) << 13)
                          + (((k_g >> 3) & 3) << 11) + ((n_g & 255) << 3) + (k_g & 7);

        if (j > i) { Wh[widx] = 0; return; }

        __shared__ float2 Bs[16][16];
        __shared__ float2 M[16][16];
        Bs[k][l] = make_float2(Bre[t], Bim[t]);
        M[k][l]  = make_float2(k == l ? 1.f : 0.f, 0.f);
        const int delta = i - j;
        __syncthreads();

        #pragma unroll
        for (int d = 0; d < 6; ++d) {
            const int s = 1 << d;
            if (delta & s) {
                const float lr = Lre[k], li = Lim[k];
                const float2 m0 = M[k][l];
                M[k][l] = make_float2(lr * m0.x - li * m0.y, lr * m0.y + li * m0.x);
                __syncthreads();
            } else if (j + (delta & (s - 1)) >= s) {
                float2 acc = make_float2(0.f, 0.f);
                #pragma unroll
                for (int m = 0; m < 16; ++m) {
                    const float2 b = Bs[k][m], v = M[m][l];
                    acc.x += b.x * v.x - b.y * v.y;
                    acc.y += b.x * v.y + b.y * v.x;
                }
                __syncthreads();
                M[k][l] = acc;
                __syncthreads();
            }
        }

        float w = 0.f;
        #pragma unroll
        for (int m = 0; m < 16; ++m) {
            const float2 v = M[m][l];
            w += Cre[k * 16 + m] * v.x - Cim[k * 16 + m] * v.y;
        }
        if (i == j) w += Dm[t];
        Wh[widx] = f2bf_rne(w);
    } else {
        // ---- split X tile (mt, kc) -> bf16 kg-major tiled layout ----
        const int sid = blockIdx.x - 4096;
        const int mt = sid >> 5;           // 128-row tile (0..255)
        const int kc = sid & 31;           // 32-col chunk
        const size_t tb = ((size_t)(mt * 32 + kc)) << 12;

        #pragma unroll
        for (int p = 0; p < 4; ++p) {
            const int f = p * 256 + t;          // float4 id in [0,1024)
            const int row = f >> 3, c4 = f & 7;
            const float4 v = *reinterpret_cast<const float4*>(
                X + (size_t)(mt * 128 + row) * 1024 + kc * 32 + c4 * 4);
            ushort4 hv;
            hv.x = f2bf_rne(v.x);
            hv.y = f2bf_rne(v.y);
            hv.z = f2bf_rne(v.z);
            hv.w = f2bf_rne(v.w);
            const size_t o = tb + ((size_t)(c4 >> 1) << 10) + (row << 3) + ((c4 & 1) << 2);
            *reinterpret_cast<ushort4*>(Xh + o) = hv;
        }
    }
}

// ---- main GEMM: 128x256, triple-buffer, counted vmcnt(6), 1 barrier/tile ---
__global__ __launch_bounds__(256, 2) void gemm_cnt_kernel(
    const unsigned short* __restrict__ Xh,
    const unsigned short* __restrict__ Wh,
    float* __restrict__ Y, int mtiles)
{
    __shared__ alignas(16) unsigned short sA[3][4096];   // 24 KB
    __shared__ alignas(16) unsigned short sB[3][8192];   // 48 KB

    const int bid = blockIdx.x;
    const int sb = 3 - bid / mtiles;   // 256-col supertile, heavy first (LPT)
    const int mt = bid % mtiles;
    const int t = threadIdx.x;
    const int wid = t >> 6, lane = t & 63;
    const int wr = wid >> 1, wc = wid & 1;     // 2Mx2N wave grid
    const int l15 = lane & 15, lg = lane >> 4;
    const int nt = (sb + 1) * 8;       // K-tiles of 32 (8,16,24,32)

    f32x4 acc[4][8] = {};

    // fragment offsets (ushorts) within a tile
    int afo[4], bfo[8];
    #pragma unroll
    for (int mm = 0; mm < 4; ++mm)
        afo[mm] = (lg << 10) + ((wr * 64 + mm * 16 + l15) << 3);
    #pragma unroll
    for (int nn = 0; nn < 8; ++nn)
        bfo[nn] = (lg << 11) + ((wc * 128 + nn * 16 + l15) << 3);

    auto stageT = [&](int b3, int tk) {        // 6 gld_lds16 per thread
        unsigned short* bA = sA[b3];
        unsigned short* bB = sB[b3];
        const unsigned short* xa = Xh + (((size_t)(mt * 32 + tk)) << 12);
        const unsigned short* wb = Wh + (((size_t)(sb * 32 + tk)) << 13);
        gld_lds16(xa + t * 8,        bA + t * 8);
        gld_lds16(xa + 2048 + t * 8, bA + 2048 + t * 8);
        gld_lds16(wb + t * 8,        bB + t * 8);
        gld_lds16(wb + 2048 + t * 8, bB + 2048 + t * 8);
        gld_lds16(wb + 4096 + t * 8, bB + 4096 + t * 8);
        gld_lds16(wb + 6144 + t * 8, bB + 6144 + t * 8);
    };

    // prologue: tiles 0,1 in flight; wait tile 0 only (6 remain in flight)
    stageT(0, 0);
    stageT(1, 1);
    asm volatile("s_waitcnt vmcnt(6)" ::: "memory");
    __builtin_amdgcn_sched_barrier(0);
    __builtin_amdgcn_s_barrier();
    __builtin_amdgcn_sched_barrier(0);

    int c = 0, c2 = 2;                 // tk%3, (tk+2)%3
    for (int tk = 0; tk < nt; ++tk) {
        if (tk + 2 < nt) stageT(c2, tk + 2);

        short8v ah[4], bh[8];
        #pragma unroll
        for (int mm = 0; mm < 4; ++mm)
            ah[mm] = *reinterpret_cast<const short8v*>(sA[c] + afo[mm]);
        #pragma unroll
        for (int nn = 0; nn < 8; ++nn)
            bh[nn] = *reinterpret_cast<const short8v*>(sB[c] + bfo[nn]);

        __builtin_amdgcn_s_setprio(1);
        #pragma unroll
        for (int mm = 0; mm < 4; ++mm)
            #pragma unroll
            for (int nn = 0; nn < 8; ++nn)
                acc[mm][nn] = __builtin_amdgcn_mfma_f32_16x16x32_bf16(
                    ah[mm], bh[nn], acc[mm][nn], 0, 0, 0);
        __builtin_amdgcn_s_setprio(0);

        if (tk + 1 < nt) {             // tile boundary
            if (tk + 2 < nt) {
                asm volatile("s_waitcnt vmcnt(6)" ::: "memory");  // t+1 landed,
            } else {                                              // t+2 in flight
                asm volatile("s_waitcnt vmcnt(0)" ::: "memory");  // tail only
            }
            __builtin_amdgcn_sched_barrier(0);
            __builtin_amdgcn_s_barrier();
            __builtin_amdgcn_sched_barrier(0);
        }
        c = (c == 2) ? 0 : c + 1;
        c2 = (c2 == 2) ? 0 : c2 + 1;
    }

    // ---- epilogue: C/D layout col=lane&15, row=(lane>>4)*4+q ----
    #pragma unroll
    for (int mm = 0; mm < 4; ++mm) {
        const int grow = mt * 128 + wr * 64 + mm * 16 + lg * 4;
        #pragma unroll
        for (int nn = 0; nn < 8; ++nn) {
            const int gcol = sb * 256 + wc * 128 + nn * 16 + l15;
            #pragma unroll
            for (int q = 0; q < 4; ++q)
                Y[(size_t)(grow + q) * 1024 + gcol] = acc[mm][nn][q];
        }
    }
}

} // namespace

extern "C" void kernel_launch(void* const* d_in, const int* in_sizes, int n_in,
                              void* d_out, int out_size, void* d_ws, size_t ws_size,
                              hipStream_t stream) {
    const float* x   = (const float*)d_in[0];
    const float* Lre = (const float*)d_in[1];
    const float* Lim = (const float*)d_in[2];
    const float* Bre = (const float*)d_in[3];
    const float* Bim = (const float*)d_in[4];
    const float* Cre = (const float*)d_in[5];
    const float* Cim = (const float*)d_in[6];
    const float* Dm  = (const float*)d_in[7];
    float* y = (float*)d_out;

    const int positions = in_sizes[0] / 1024;          // 32768
    const int mtiles = positions / 128;                // 256

    unsigned short* Wh = (unsigned short*)d_ws;        // 2 MB
    unsigned short* Xh = Wh + 1024 * 1024;             // 64 MB

    prep_kernel<<<4096 + mtiles * 32, 256, 0, stream>>>(
        x, Lre, Lim, Bre, Bim, Cre, Cim, Dm, Wh, Xh);
    gemm_cnt_kernel<<<mtiles * 4, 256, 0, stream>>>(Xh, Wh, y, mtiles);
}